// Round 3
// baseline (634.365 us; speedup 1.0000x reference)
//
#include <hip/hip_runtime.h>
#include <hip/hip_bf16.h>

#define D 128

typedef __bf16 bf16x8 __attribute__((ext_vector_type(8)));
typedef float f32x4 __attribute__((ext_vector_type(4)));
typedef unsigned int u32x4 __attribute__((ext_vector_type(4)));
typedef unsigned short u16x4_t __attribute__((ext_vector_type(4)));
typedef unsigned short u16x8_t __attribute__((ext_vector_type(8)));

__device__ __forceinline__ float b2f(unsigned short u) {
    unsigned int x = ((unsigned int)u) << 16;
    return __builtin_bit_cast(float, x);
}
__device__ __forceinline__ unsigned short f2b(float f) {
    __hip_bfloat16 h = __float2bfloat16(f);
    return __builtin_bit_cast(unsigned short, h);
}

__device__ __forceinline__ void acc8(float* acc, u32x4 x) {
#pragma unroll
    for (int r = 0; r < 4; ++r) {
        acc[2 * r]     += __builtin_bit_cast(float, x[r] << 16);
        acc[2 * r + 1] += __builtin_bit_cast(float, x[r] & 0xffff0000u);
    }
}

// ---------------- CSR build ----------------
__global__ void hist_kernel(const int* __restrict__ dst, int* __restrict__ counts, int E) {
    int e = blockIdx.x * blockDim.x + threadIdx.x;
    if (e < E) atomicAdd(&counts[dst[e]], 1);
}

__global__ void block_sums_kernel(const int* __restrict__ counts, int* __restrict__ bsum, int N) {
    __shared__ int s[256];
    int b = blockIdx.x, t = threadIdx.x;
    int i0 = b * 1024 + t * 4;
    int v = 0;
#pragma unroll
    for (int j = 0; j < 4; ++j)
        if (i0 + j < N) v += counts[i0 + j];
    s[t] = v;
    __syncthreads();
    for (int off = 128; off > 0; off >>= 1) {
        if (t < off) s[t] += s[t + off];
        __syncthreads();
    }
    if (t == 0) bsum[b] = s[0];
}

__global__ void scan_kernel(const int* __restrict__ counts, const int* __restrict__ bsum,
                            int* __restrict__ row_ptr, int N, int nb, int E) {
    __shared__ int sb[128];
    __shared__ int sth[256];
    int b = blockIdx.x, t = threadIdx.x;
    if (t < nb) sb[t] = bsum[t];
    __syncthreads();
    if (t == 0) {
        int run = 0;
        for (int i = 0; i < nb; ++i) { int v = sb[i]; sb[i] = run; run += v; }
    }
    __syncthreads();
    int base = sb[b];
    int i0 = b * 1024 + t * 4;
    int c[4];
    int ls = 0;
#pragma unroll
    for (int j = 0; j < 4; ++j) {
        c[j] = (i0 + j < N) ? counts[i0 + j] : 0;
        ls += c[j];
    }
    sth[t] = ls;
    __syncthreads();
    for (int off = 1; off < 256; off <<= 1) {
        int v = (t >= off) ? sth[t - off] : 0;
        __syncthreads();
        sth[t] += v;
        __syncthreads();
    }
    int run = sth[t] - ls + base;
#pragma unroll
    for (int j = 0; j < 4; ++j) {
        if (i0 + j < N) row_ptr[i0 + j] = run;
        run += c[j];
    }
    if (b == 0 && t == 0) row_ptr[N] = E;
}

__global__ void scatter_kernel(const int* __restrict__ src, const int* __restrict__ dst,
                               const int* __restrict__ row_ptr, int* __restrict__ cursor,
                               int* __restrict__ col, int E) {
    int e = blockIdx.x * blockDim.x + threadIdx.x;
    if (e < E) {
        int d = dst[e];
        int slot = row_ptr[d] + atomicAdd(&cursor[d], 1);
        col[slot] = src[e];
    }
}

// ---------------- dtype conversion ----------------
__global__ void f32_to_bf16_kernel(const float4* __restrict__ in, ushort4* __restrict__ out, int n4) {
    int i = blockIdx.x * blockDim.x + threadIdx.x;
    if (i < n4) {
        float4 f = in[i];
        ushort4 o;
        o.x = f2b(f.x); o.y = f2b(f.y); o.z = f2b(f.z); o.w = f2b(f.w);
        out[i] = o;
    }
}

// W[l][k][n] row-major -> frag-blocked bf16: for frag (nt,kb), 64 lanes x 16B.
// Unit for lane (l15,lg) holds W[k=kb*32+lg*8 .. +7][n=nt*16+l15] (i.e. WT[n][k..k+7]).
// flat short idx = ((l*32 + nt*4 + kb)*64 + lg*16 + l15)*8 + j
__global__ void wtrans_kernel(const float* __restrict__ W1, const float* __restrict__ W2,
                              unsigned short* __restrict__ W1L, unsigned short* __restrict__ W2L,
                              int total) {
    int i = blockIdx.x * blockDim.x + threadIdx.x;
    if (i < total) {
        int l = i >> 14;
        int rem = i & 16383;
        int k = rem >> 7;
        int n = rem & 127;
        int nt = n >> 4, l15 = n & 15;
        int kb = k >> 5, lg = (k >> 3) & 3, j = k & 7;
        int o = ((l * 32 + nt * 4 + kb) * 64 + lg * 16 + l15) * 8 + j;
        W1L[o] = f2b(W1[i]);
        W2L[o] = f2b(W2[i]);
    }
}

// ---------------- fused GIN layer ----------------
// Per wave: aggregate 16 nodes -> LDS tile (A-frag-blocked, padded), then
// two swapped MFMA GEMMs (W frags from global as A-operand, tile as B-operand).
// Padded tile layout: 16B unit U(m,k) = (k/32)*80 + m*5 + (k%32)/8; byte = U*16 + (k%8)*2.
__global__ __launch_bounds__(256, 4) void fused_layer_kernel(
        const unsigned short* __restrict__ hIn, const int* __restrict__ row_ptr,
        const int* __restrict__ col, const unsigned short* __restrict__ W1L,
        const unsigned short* __restrict__ W2L, const float* __restrict__ b1,
        const float* __restrict__ b2, unsigned short* __restrict__ hOut,
        float* __restrict__ fOut, int mode, int N) {
    __shared__ float b1s[128], b2s[128];
    __shared__ unsigned short tilebuf[4 * 2560];  // 4 waves x 5120B

    int tid = threadIdx.x;
    if (tid < 128) b1s[tid] = b1[tid];
    else b2s[tid - 128] = b2[tid - 128];
    __syncthreads();

    int wave = tid >> 6;
    int lane = tid & 63;
    int l15 = lane & 15;
    int lg = lane >> 4;
    int tile = blockIdx.x * 4 + wave;
    int v0 = tile * 16;
    if (v0 >= N) return;
    unsigned short* buf = tilebuf + wave * 2560;

    // ---- aggregation: rst rows -> buf ----
    // lane roles: i=l15 feature block (8 bf16), j=lg edge slot
    for (int t = 0; t < 16; ++t) {
        int v = v0 + t;
        if (v >= N) break;
        int e0 = row_ptr[v], e1 = row_ptr[v + 1];
        float accA[8], accB[8];
#pragma unroll
        for (int r = 0; r < 8; ++r) { accA[r] = 0.f; accB[r] = 0.f; }
        if (lg == 0) {
            u32x4 x = *(const u32x4*)(hIn + (size_t)v * D + l15 * 8);
            acc8(accA, x);
        }
        int e = e0 + lg;
        for (; e + 4 < e1; e += 8) {
            int u0 = col[e];
            int u1 = col[e + 4];
            u32x4 x0 = *(const u32x4*)(hIn + (size_t)u0 * D + l15 * 8);
            u32x4 x1 = *(const u32x4*)(hIn + (size_t)u1 * D + l15 * 8);
            acc8(accA, x0);
            acc8(accB, x1);
        }
        if (e < e1) {
            u32x4 x0 = *(const u32x4*)(hIn + (size_t)col[e] * D + l15 * 8);
            acc8(accA, x0);
        }
        unsigned short pk[8];
#pragma unroll
        for (int r = 0; r < 8; ++r) {
            float s = accA[r] + accB[r];
            s += __shfl_xor(s, 16);
            s += __shfl_xor(s, 32);
            pk[r] = f2b(s);
        }
        if (lg == 0) {
            // k = l15*8: kb=l15/4, lgk=l15%4
            int U = (l15 >> 2) * 80 + t * 5 + (l15 & 3);
            u16x8_t o;
#pragma unroll
            for (int r = 0; r < 8; ++r) o[r] = pk[r];
            *(u16x8_t*)(buf + U * 8) = o;
        }
    }

    // ---- GEMM1 (swapped): h1[m][n1] = act(rst @ W1 + b1); lane gets m=l15, n1=nt*16+lg*4+r ----
    bf16x8 bfragT[4];
#pragma unroll
    for (int kb = 0; kb < 4; ++kb)
        bfragT[kb] = *(const bf16x8*)(buf + (kb * 80 + l15 * 5 + lg) * 8);

    f32x4 acc[8];
#pragma unroll
    for (int nt = 0; nt < 8; ++nt) acc[nt] = (f32x4){0.f, 0.f, 0.f, 0.f};
#pragma unroll
    for (int kb = 0; kb < 4; ++kb)
#pragma unroll
        for (int nt = 0; nt < 8; ++nt) {
            bf16x8 wf = *(const bf16x8*)(W1L + ((nt * 4 + kb) * 64 + lane) * 8);
            acc[nt] = __builtin_amdgcn_mfma_f32_16x16x32_bf16(wf, bfragT[kb], acc[nt], 0, 0, 0);
        }
#pragma unroll
    for (int nt = 0; nt < 8; ++nt) {
        f32x4 bias = *(const f32x4*)(b1s + nt * 16 + lg * 4);
        // write h1[m=l15][n1=nt*16+lg*4+r], 4 consecutive n1 -> b64
        int kb2 = nt >> 1;
        int lgk = (nt & 1) * 2 + (lg >> 1);
        int U = kb2 * 80 + l15 * 5 + lgk;
        u16x4_t o;
#pragma unroll
        for (int r = 0; r < 4; ++r) {
            float x = acc[nt][r] + bias[r];
            if (mode == 0) x = fmaxf(x, 0.f);
            o[r] = f2b(x);
        }
        *(u16x4_t*)(buf + U * 8 + (lg & 1) * 4) = o;
    }

    // ---- GEMM2 (swapped): h2[m][n2]; lane gets m=l15, n2=nt*16+lg*4+r ----
    bf16x8 bfragT2[4];
#pragma unroll
    for (int kb = 0; kb < 4; ++kb)
        bfragT2[kb] = *(const bf16x8*)(buf + (kb * 80 + l15 * 5 + lg) * 8);

#pragma unroll
    for (int nt = 0; nt < 8; ++nt) acc[nt] = (f32x4){0.f, 0.f, 0.f, 0.f};
#pragma unroll
    for (int kb = 0; kb < 4; ++kb)
#pragma unroll
        for (int nt = 0; nt < 8; ++nt) {
            bf16x8 wf = *(const bf16x8*)(W2L + ((nt * 4 + kb) * 64 + lane) * 8);
            acc[nt] = __builtin_amdgcn_mfma_f32_16x16x32_bf16(wf, bfragT2[kb], acc[nt], 0, 0, 0);
        }
    int m = v0 + l15;
    if (m < N) {
#pragma unroll
        for (int nt = 0; nt < 8; ++nt) {
            f32x4 bias = *(const f32x4*)(b2s + nt * 16 + lg * 4);
            int c0 = nt * 16 + lg * 4;
            if (mode == 0) {
                u16x4_t o;
#pragma unroll
                for (int r = 0; r < 4; ++r)
                    o[r] = f2b(fmaxf(acc[nt][r] + bias[r], 0.f));
                *(u16x4_t*)(hOut + (size_t)m * D + c0) = o;
            } else {
                f32x4 o;
#pragma unroll
                for (int r = 0; r < 4; ++r) o[r] = acc[nt][r] + bias[r];
                *(f32x4*)(fOut + (size_t)m * D + c0) = o;
            }
        }
    }
}

extern "C" void kernel_launch(void* const* d_in, const int* in_sizes, int n_in,
                              void* d_out, int out_size, void* d_ws, size_t ws_size,
                              hipStream_t stream) {
    const float* feat = (const float*)d_in[0];
    const float* W1 = (const float*)d_in[1];
    const float* b1 = (const float*)d_in[2];
    const float* W2 = (const float*)d_in[3];
    const float* b2 = (const float*)d_in[4];
    const int* src = (const int*)d_in[5];
    const int* dst = (const int*)d_in[6];

    const int N = in_sizes[0] / D;
    const int L = in_sizes[2] / D;
    const int E = in_sizes[5];

    char* w = (char*)d_ws;
    size_t off = 0;
    auto alloc = [&](size_t bytes) {
        void* p = w + off;
        off = (off + bytes + 255) & ~(size_t)255;
        return p;
    };
    unsigned short* bufA = (unsigned short*)alloc((size_t)N * D * 2);
    unsigned short* bufB = (unsigned short*)alloc((size_t)N * D * 2);
    int* col = (int*)alloc((size_t)E * 4);
    int* row_ptr = (int*)alloc((size_t)(N + 1) * 4);
    int* counts = (int*)alloc((size_t)N * 4);
    unsigned short* W1L = (unsigned short*)alloc((size_t)L * 16384 * 2);
    unsigned short* W2L = (unsigned short*)alloc((size_t)L * 16384 * 2);
    int* bsum = (int*)alloc(512);

    int nb = (N + 1023) / 1024;

    hipMemsetAsync(counts, 0, (size_t)N * 4, stream);
    hist_kernel<<<(E + 255) / 256, 256, 0, stream>>>(dst, counts, E);
    block_sums_kernel<<<nb, 256, 0, stream>>>(counts, bsum, N);
    scan_kernel<<<nb, 256, 0, stream>>>(counts, bsum, row_ptr, N, nb, E);
    hipMemsetAsync(counts, 0, (size_t)N * 4, stream);
    scatter_kernel<<<(E + 255) / 256, 256, 0, stream>>>(src, dst, row_ptr, counts, col, E);

    int n4 = N * D / 4;
    f32_to_bf16_kernel<<<(n4 + 255) / 256, 256, 0, stream>>>((const float4*)feat, (ushort4*)bufA, n4);
    int wtotal = L * D * D;
    wtrans_kernel<<<(wtotal + 255) / 256, 256, 0, stream>>>(W1, W2, W1L, W2L, wtotal);

    int ntiles = (N + 15) / 16;
    int grid = (ntiles + 3) / 4;
    const unsigned short* hin[3] = {bufA, bufB, bufA};
    unsigned short* hout[3] = {bufB, bufA, nullptr};
    for (int i = 0; i < L; ++i) {
        int mode = (i == L - 1) ? 1 : 0;
        fused_layer_kernel<<<grid, 256, 0, stream>>>(
            hin[i], row_ptr, col, W1L + (size_t)i * 16384, W2L + (size_t)i * 16384,
            b1 + i * D, b2 + i * D, hout[i], (float*)d_out, mode, N);
    }
}